// Round 7
// baseline (128.785 us; speedup 1.0000x reference)
//
#include <hip/hip_runtime.h>
#include <hip/hip_bf16.h>

// BPTT diagonal RNN: u = X @ B^T (bf16 MFMA), then chunked diagonal scan.
// R7: back to R3's proven separated pipeline. Fast coalesced cvt (16B-load /
// 8B-store per lane, one launch) + gemm8p with corrected LDS swizzle
// (ks ^ ((r>>1)&3): 2-way free instead of 4-way conflict). 4-slot ring,
// counted vmcnt(8), raw barriers, setprio, XCD swizzle — unchanged from R3.

#define TDIM 8192
#define HDIM 2048
#define BM 256
#define BN 256
#define BK 32
#define NT (HDIM / BK)         // 64 K-tiles
#define ASLOT 8192             // shorts per A slot (256*32)
#define BSLOT 8192
#define LCH 64                 // scan chunk length
#define GCH (TDIM / LCH)       // 128 chunks

#define XBF_BYTES (TDIM * HDIM * 2)
#define BBF_BYTES (HDIM * HDIM * 2)
#define E_BYTES   (GCH * HDIM * 4)
#define WS_NEED   ((size_t)XBF_BYTES + BBF_BYTES + E_BYTES)

typedef float f32x4 __attribute__((ext_vector_type(4)));
typedef short s16x4 __attribute__((ext_vector_type(4)));
typedef short s16x8 __attribute__((ext_vector_type(8)));

static __device__ __forceinline__ short f2bf(float f) {
  __bf16 b = (__bf16)f;
  return __builtin_bit_cast(short, b);
}

#define SB()   asm volatile("s_barrier" ::: "memory")
#define VMW(n) asm volatile("s_waitcnt vmcnt(" #n ")" ::: "memory")
#define GL(gp, lp)                                                            \
  __builtin_amdgcn_global_load_lds(                                           \
      (const __attribute__((address_space(1))) void*)(gp),                    \
      (__attribute__((address_space(3))) void*)(lp), 16, 0, 0)

// ---------------- fused fast f32->bf16 convert: X and B, one launch ---------
// 16B contiguous load/lane, 8B contiguous store/lane (fully coalesced).
__global__ void cvt_fast(const float* __restrict__ X, const float* __restrict__ Bm,
                         short* __restrict__ Xb, short* __restrict__ Bb) {
  const int XN4 = TDIM * HDIM / 4;      // 4194304
  const int BN4 = HDIM * HDIM / 4;      // 1048576
  const int stride = gridDim.x * blockDim.x;
  for (int i = blockIdx.x * blockDim.x + threadIdx.x; i < XN4 + BN4; i += stride) {
    const float* s;
    short* d;
    int k;
    if (i < XN4) { s = X;  d = Xb; k = i; }
    else         { s = Bm; d = Bb; k = i - XN4; }
    f32x4 v = *(const f32x4*)(s + (size_t)k * 4);
    s16x4 o;
    o[0] = f2bf(v[0]); o[1] = f2bf(v[1]); o[2] = f2bf(v[2]); o[3] = f2bf(v[3]);
    *(s16x4*)(d + (size_t)k * 4) = o;
  }
}

// ---------------- deep-pipelined 256^2 GEMM: U = Xb @ Bb^T (R3 + swizzle fix)
// 8 waves (2Mx4N), per-wave 128x64 out. BK=32, 4-slot LDS ring (128 KiB).
// Iter j: compute K-tile j (slot j&3), stage K-tile j+3 (slot (j-1)&3).
// vmcnt(8) at iter end gates K-tile j+1. LDS granule swizzle: phys = logical ^
// ((row>>1)&3) -> each 16-lane ds_read_b128 phase hits 8 granules 2-way (free).
__global__ __launch_bounds__(512, 2) void gemm8p2(
    const short* __restrict__ Xb, const short* __restrict__ Bb,
    float* __restrict__ U) {
  extern __shared__ __align__(16) short smem[];
  short* As = smem;             // 4 slots x 8192 shorts (64 KiB)
  short* Bs = smem + 4 * ASLOT; // 4 slots x 8192 shorts (64 KiB)

  // XCD-aware swizzle: nwg=256, each XCD gets a 4(tm) x 8(tn) rectangle
  const int wg  = blockIdx.x;
  const int swz = (wg & 7) * 32 + (wg >> 3);
  const int tm = swz >> 3;              // 0..31
  const int tn = swz & 7;               // 0..7
  const int row0 = tm * BM, col0 = tn * BN;

  const int tid  = threadIdx.x;
  const int lane = tid & 63;
  const int wid  = tid >> 6;
  const int wr = (wid >> 2) * 128;      // 2 m-groups
  const int wc = (wid & 3) * 64;        // 4 n-groups
  const int r16 = lane & 15;
  const int ks8 = (lane >> 4) * 8;      // 16B k-slice (shorts)

  // fragment read offsets (within slot): phys granule = ks ^ ((r>>1)&3)
  int offA[8], offB[4];
#pragma unroll
  for (int m = 0; m < 8; ++m) {
    const int r = wr + m * 16 + r16;
    offA[m] = r * BK + (ks8 ^ (((r >> 1) & 3) * 8));
  }
#pragma unroll
  for (int n = 0; n < 4; ++n) {
    const int r = wc + n * 16 + r16;
    offB[n] = r * BK + (ks8 ^ (((r >> 1) & 3) * 8));
  }

  // staging: unit = 128 rows x 32 k (8 KiB) = 1 gload_lds/thread.
  // LDS dest linear tid*16B (row=tid>>2, phys granule=tid&3); global source
  // pre-swizzled: logical chunk = (tid&3) ^ swz(row) = (tid&3) ^ ((tid>>3)&3).
  const int srow = tid >> 2;            // 0..127
  const int sg   = (tid & 3) ^ ((tid >> 3) & 3);
  const short* gA0 = Xb + (size_t)(row0 + srow) * HDIM + sg * 8;
  const short* gA1 = gA0 + (size_t)128 * HDIM;
  const short* gB0 = Bb + (size_t)(col0 + srow) * HDIM + sg * 8;
  const short* gB1 = gB0 + (size_t)128 * HDIM;

  f32x4 acc[8][4] = {};

  // prologue: stage K-tiles 0,1,2 -> slots 0,1,2 (12 loads), wait K0, barrier
#pragma unroll
  for (int k = 0; k < 3; ++k) {
    GL(gA0 + k * BK, &As[k * ASLOT + tid * 8]);
    GL(gA1 + k * BK, &As[k * ASLOT + 4096 + tid * 8]);
    GL(gB0 + k * BK, &Bs[k * BSLOT + tid * 8]);
    GL(gB1 + k * BK, &Bs[k * BSLOT + 4096 + tid * 8]);
  }
  VMW(8);
  SB();

#define ITER(J_, ST_, VMA_, SBF_) do {                                        \
    const int sc_ = (J_) & 3;                                                 \
    const int si_ = ((J_) + 3) & 3;                                           \
    const int ko_ = ((J_) + 3) * BK;                                          \
    s16x8 af[4], bfv[4];                                                      \
    _Pragma("unroll") for (int m = 0; m < 4; ++m)                             \
      af[m] = *(const s16x8*)&As[sc_ * ASLOT + offA[m]];                      \
    _Pragma("unroll") for (int n = 0; n < 4; ++n)                             \
      bfv[n] = *(const s16x8*)&Bs[sc_ * BSLOT + offB[n]];                     \
    if (ST_) {                                                                \
      GL(gA0 + ko_, &As[si_ * ASLOT + tid * 8]);                              \
      GL(gA1 + ko_, &As[si_ * ASLOT + 4096 + tid * 8]);                       \
    }                                                                         \
    SB();                                                                     \
    __builtin_amdgcn_s_setprio(1);                                            \
    _Pragma("unroll") for (int m = 0; m < 4; ++m)                             \
      _Pragma("unroll") for (int n = 0; n < 4; ++n)                           \
        acc[m][n] = __builtin_amdgcn_mfma_f32_16x16x32_bf16(                  \
            af[m], bfv[n], acc[m][n], 0, 0, 0);                               \
    __builtin_amdgcn_s_setprio(0);                                            \
    SB();                                                                     \
    _Pragma("unroll") for (int m = 0; m < 4; ++m)                             \
      af[m] = *(const s16x8*)&As[sc_ * ASLOT + offA[4 + m]];                  \
    if (ST_) {                                                                \
      GL(gB0 + ko_, &Bs[si_ * BSLOT + tid * 8]);                              \
      GL(gB1 + ko_, &Bs[si_ * BSLOT + 4096 + tid * 8]);                       \
    }                                                                         \
    SB();                                                                     \
    __builtin_amdgcn_s_setprio(1);                                            \
    _Pragma("unroll") for (int m = 0; m < 4; ++m)                             \
      _Pragma("unroll") for (int n = 0; n < 4; ++n)                           \
        acc[4 + m][n] = __builtin_amdgcn_mfma_f32_16x16x32_bf16(              \
            af[m], bfv[n], acc[4 + m][n], 0, 0, 0);                           \
    __builtin_amdgcn_s_setprio(0);                                            \
    VMA_;                                                                     \
    SBF_;                                                                     \
  } while (0)

#pragma unroll 4
  for (int j = 0; j < NT - 4; ++j) ITER(j, true, VMW(8), SB());
  ITER(NT - 4, true,  VMW(8), SB());   // stages K-tile NT-1
  ITER(NT - 3, false, VMW(4), SB());
  ITER(NT - 2, false, VMW(0), SB());
  ITER(NT - 1, false, (void)0, (void)0);
#undef ITER

  // epilogue: C/D mapping col=lane&15, row=(lane>>4)*4+j [verified R1-R6]
  const int crow = row0 + wr + ((lane >> 4) << 2);
  const int ccol = col0 + wc + r16;
#pragma unroll
  for (int m = 0; m < 8; ++m)
#pragma unroll
    for (int n = 0; n < 4; ++n)
#pragma unroll
      for (int j = 0; j < 4; ++j)
        U[(size_t)(crow + m * 16 + j) * HDIM + ccol + n * 16] = acc[m][n][j];
}

// ---------------- fallback GEMM (R1, f32 reg-staging, proven) ---------------
__global__ __launch_bounds__(256, 2) void gemm_f32_fb(
    const float* __restrict__ X, const float* __restrict__ Bm,
    float* __restrict__ U) {
#define LDK 40
#define FBM 128
#define FBK 32
#define FNT (HDIM / FBK)
  __shared__ __align__(16) short As[2][FBM * LDK];
  __shared__ __align__(16) short Bs[2][FBM * LDK];
  const int wg  = blockIdx.x;
  const int cpx = (TDIM / FBM) * (HDIM / FBM) / 8;
  const int swz = (wg & 7) * cpx + (wg >> 3);
  const int tm = swz >> 4;
  const int tn = swz & 15;
  const int row0 = tm * FBM, col0 = tn * FBM;
  const int tid  = threadIdx.x;
  const int lane = tid & 63;
  const int wid  = tid >> 6;
  const int wr = (wid >> 1) * 64;
  const int wc = (wid & 1) * 64;
  const int srow = tid >> 2;
  const int sk   = (tid & 3) << 3;
  const float* gA  = X  + (size_t)(row0 + srow) * HDIM + sk;
  const float* gA2 = gA + 64 * HDIM;
  const float* gB  = Bm + (size_t)(col0 + srow) * HDIM + sk;
  const float* gB2 = gB + 64 * HDIM;
  f32x4 a00, a01, a10, a11, b00, b01, b10, b11;
#define LOADREG(kt) do {                                                      \
    const float* p;                                                           \
    p = gA  + (kt) * FBK; a00 = *(const f32x4*)p; a01 = *(const f32x4*)(p+4); \
    p = gA2 + (kt) * FBK; a10 = *(const f32x4*)p; a11 = *(const f32x4*)(p+4); \
    p = gB  + (kt) * FBK; b00 = *(const f32x4*)p; b01 = *(const f32x4*)(p+4); \
    p = gB2 + (kt) * FBK; b10 = *(const f32x4*)p; b11 = *(const f32x4*)(p+4); \
  } while (0)
#define CVT8(v, lo, hi) do {                                                  \
    v[0] = f2bf(lo[0]); v[1] = f2bf(lo[1]); v[2] = f2bf(lo[2]);               \
    v[3] = f2bf(lo[3]); v[4] = f2bf(hi[0]); v[5] = f2bf(hi[1]);               \
    v[6] = f2bf(hi[2]); v[7] = f2bf(hi[3]);                                   \
  } while (0)
#define DSWRITE(buf) do {                                                     \
    s16x8 v;                                                                  \
    CVT8(v, a00, a01); *(s16x8*)&As[buf][srow * LDK + sk] = v;                \
    CVT8(v, a10, a11); *(s16x8*)&As[buf][(srow + 64) * LDK + sk] = v;         \
    CVT8(v, b00, b01); *(s16x8*)&Bs[buf][srow * LDK + sk] = v;                \
    CVT8(v, b10, b11); *(s16x8*)&Bs[buf][(srow + 64) * LDK + sk] = v;         \
  } while (0)
  f32x4 acc[4][4] = {};
#define COMPUTE(buf) do {                                                     \
    const int r16_ = lane & 15;                                               \
    const int ks_  = (lane >> 4) * 8;                                         \
    s16x8 af[4], bfr[4];                                                      \
    _Pragma("unroll") for (int m = 0; m < 4; ++m)                             \
      af[m] = *(const s16x8*)&As[buf][(wr + m * 16 + r16_) * LDK + ks_];      \
    _Pragma("unroll") for (int n = 0; n < 4; ++n)                             \
      bfr[n] = *(const s16x8*)&Bs[buf][(wc + n * 16 + r16_) * LDK + ks_];     \
    _Pragma("unroll") for (int m = 0; m < 4; ++m)                             \
      _Pragma("unroll") for (int n = 0; n < 4; ++n)                           \
        acc[m][n] = __builtin_amdgcn_mfma_f32_16x16x32_bf16(                  \
            af[m], bfr[n], acc[m][n], 0, 0, 0);                               \
  } while (0)
  LOADREG(0);
  DSWRITE(0);
  __syncthreads();
#pragma unroll 2
  for (int kt = 0; kt < FNT; ++kt) {
    const int cur = kt & 1;
    if (kt + 1 < FNT) LOADREG(kt + 1);
    COMPUTE(cur);
    if (kt + 1 < FNT) DSWRITE(cur ^ 1);
    __syncthreads();
  }
  const int crow = wr + ((lane >> 4) << 2);
  const int ccol = wc + (lane & 15);
#pragma unroll
  for (int m = 0; m < 4; ++m)
#pragma unroll
    for (int n = 0; n < 4; ++n)
#pragma unroll
      for (int j = 0; j < 4; ++j)
        U[(size_t)(row0 + crow + m * 16 + j) * HDIM + (col0 + ccol + n * 16)] =
            acc[m][n][j];
#undef LOADREG
#undef CVT8
#undef DSWRITE
#undef COMPUTE
#undef LDK
#undef FBM
#undef FBK
#undef FNT
}

// ---------------- scan pass 1: per-chunk local scan end values ---------------
__global__ void scan_pass1(const float* __restrict__ U,
                           const float* __restrict__ lam,
                           float* __restrict__ e) {
  const int c = (blockIdx.y * 256 + threadIdx.x) * 4;
  const int j = blockIdx.x;
  const f32x4 l4 = *(const f32x4*)&lam[c];
  f32x4 h = {0.f, 0.f, 0.f, 0.f};
  const float* up = U + (size_t)j * LCH * HDIM + c;
#pragma unroll 4
  for (int t = 0; t < LCH; ++t) {
    f32x4 u4 = *(const f32x4*)up;
    h = l4 * h + u4;
    up += HDIM;
  }
  *(f32x4*)&e[(size_t)j * HDIM + c] = h;
}

// ---------------- scan pass 2: carry scan over chunks (in-place on e) --------
__global__ void scan_carry(float* __restrict__ e, const float* __restrict__ lam) {
  const int c = (blockIdx.x * 256 + threadIdx.x) * 4;
  const f32x4 l4 = *(const f32x4*)&lam[c];
  f32x4 p = l4;
#pragma unroll
  for (int i = 0; i < 6; ++i) p = p * p;   // lam^64
  f32x4 E = {0.f, 0.f, 0.f, 0.f};
  for (int j = 0; j < GCH; ++j) {
    f32x4 ej = *(const f32x4*)&e[(size_t)j * HDIM + c];
    *(f32x4*)&e[(size_t)j * HDIM + c] = E;  // carry into chunk j = E_{j-1}
    E = p * E + ej;
  }
}

// ---------------- scan pass 3: final scan with carry, in-place U -> h --------
__global__ void scan_pass3(float* __restrict__ U, const float* __restrict__ lam,
                           const float* __restrict__ carry) {
  const int c = (blockIdx.y * 256 + threadIdx.x) * 4;
  const int j = blockIdx.x;
  const f32x4 l4 = *(const f32x4*)&lam[c];
  f32x4 h = *(const f32x4*)&carry[(size_t)j * HDIM + c];
  float* up = U + (size_t)j * LCH * HDIM + c;
#pragma unroll 4
  for (int t = 0; t < LCH; ++t) {
    f32x4 u4 = *(const f32x4*)up;
    h = l4 * h + u4;
    *(f32x4*)up = h;
    up += HDIM;
  }
}

extern "C" void kernel_launch(void* const* d_in, const int* in_sizes, int n_in,
                              void* d_out, int out_size, void* d_ws, size_t ws_size,
                              hipStream_t stream) {
  const float* X   = (const float*)d_in[0];
  const float* lam = (const float*)d_in[1];
  const float* Bm  = (const float*)d_in[2];
  float* U = (float*)d_out;              // u then h, in-place

  if (ws_size >= WS_NEED) {
    short* Xb = (short*)d_ws;
    short* Bb = (short*)((char*)d_ws + XBF_BYTES);
    float* e  = (float*)((char*)d_ws + XBF_BYTES + BBF_BYTES);

    hipFuncSetAttribute((const void*)gemm8p2,
                        hipFuncAttributeMaxDynamicSharedMemorySize, 131072);

    cvt_fast<<<dim3(2048), dim3(256), 0, stream>>>(X, Bm, Xb, Bb);
    gemm8p2<<<dim3((TDIM / BM) * (HDIM / BN)), dim3(512), 131072, stream>>>(
        Xb, Bb, U);
    scan_pass1<<<dim3(GCH, HDIM / 1024), dim3(256), 0, stream>>>(U, lam, e);
    scan_carry<<<dim3(HDIM / 1024), dim3(256), 0, stream>>>(e, lam);
    scan_pass3<<<dim3(GCH, HDIM / 1024), dim3(256), 0, stream>>>(U, lam, e);
  } else {
    float* e = (float*)d_ws;
    gemm_f32_fb<<<dim3((TDIM / 128) * (HDIM / 128)), dim3(256), 0, stream>>>(
        X, Bm, U);
    scan_pass1<<<dim3(GCH, HDIM / 1024), dim3(256), 0, stream>>>(U, lam, e);
    scan_carry<<<dim3(HDIM / 1024), dim3(256), 0, stream>>>(e, lam);
    scan_pass3<<<dim3(GCH, HDIM / 1024), dim3(256), 0, stream>>>(U, lam, e);
  }
}